// Round 3
// baseline (133.998 us; speedup 1.0000x reference)
//
#include <hip/hip_runtime.h>

#define PI_F 3.141592653f
#define NB 1024
#define NW 16            // 16 x u64 words per 1024-bit row
#define IOU_THR_F 0.1f

__device__ __forceinline__ float limit_period_f(float v) {
    return v - floorf(v / (2.0f * PI_F) + 0.5f) * (2.0f * PI_F);
}

// swizzled word index: word w of row r lives at r*16 + (w ^ (r&15))
__device__ __forceinline__ int widx(int r, int w) {
    return (r << 4) | (w ^ (r & 15));
}

// ---------------------------------------------------------------------------
// K1: per-pair rotated BEV IoU -> packed bitmask (iou > 0.1) + nonzero flags
// grid (4, 1024) x 256 threads; row i = blockIdx.y, col j = blockIdx.x*256+tid
// ---------------------------------------------------------------------------
__global__ __launch_bounds__(256) void iou_mask_kernel(
    const float* __restrict__ boxes,
    unsigned long long* __restrict__ maskrow,
    unsigned char* __restrict__ rowflag)
{
    __shared__ float vxs[2][8][256];
    __shared__ float vys[2][8][256];
    const int tid = threadIdx.x;
    const int i = blockIdx.y;
    const int j = blockIdx.x * 256 + tid;

    const float ax = boxes[i*7+0], ay = boxes[i*7+1], az = boxes[i*7+2];
    const float adx = boxes[i*7+3], ady = boxes[i*7+4], adz = boxes[i*7+5];
    const float aang = limit_period_f(boxes[i*7+6]);
    const float bx = boxes[j*7+0], by = boxes[j*7+1], bz = boxes[j*7+2];
    const float bdx = boxes[j*7+3], bdy = boxes[j*7+4], bdz = boxes[j*7+5];
    const float bang = limit_period_f(boxes[j*7+6]);

    float ca, sa, cb, sb;
    sincosf(aang, &sa, &ca);
    sincosf(bang, &sb, &cb);

    {
        const float hx = 0.5f*adx, hy = 0.5f*ady;
        const float lxs[4] = { hx, -hx, -hx, hx };
        const float lys[4] = { hy, hy, -hy, -hy };
        #pragma unroll
        for (int k = 0; k < 4; ++k) {
            vxs[0][k][tid] = lxs[k]*ca - lys[k]*sa + ax;
            vys[0][k][tid] = lxs[k]*sa + lys[k]*ca + ay;
        }
    }
    float pbx[4], pby[4];
    {
        const float hx = 0.5f*bdx, hy = 0.5f*bdy;
        const float lxs[4] = { hx, -hx, -hx, hx };
        const float lys[4] = { hy, hy, -hy, -hy };
        #pragma unroll
        for (int k = 0; k < 4; ++k) {
            pbx[k] = lxs[k]*cb - lys[k]*sb + bx;
            pby[k] = lxs[k]*sb + lys[k]*cb + by;
        }
    }

    int n = 4;
    int cur = 0;
    #pragma unroll
    for (int e = 0; e < 4; ++e) {
        const float eax = pbx[e], eay = pby[e];
        const float ebx2 = pbx[(e+1)&3], eby2 = pby[(e+1)&3];
        const float dx = ebx2 - eax, dy = eby2 - eay;
        int m = 0;
        if (n > 0) {
            int pidx = n - 1; if (pidx > 7) pidx = 7;
            float px = vxs[cur][pidx][tid];
            float py = vys[cur][pidx][tid];
            float sq = dx*(py - eay) - dy*(px - eax);
            #pragma unroll
            for (int k = 0; k < 8; ++k) {
                if (k < n) {
                    const float cx = vxs[cur][k][tid];
                    const float cy = vys[cur][k][tid];
                    const float sp = dx*(cy - eay) - dy*(cx - eax);
                    const bool in_p = (sp >= 0.0f);
                    const bool in_q = (sq >= 0.0f);
                    if (in_p != in_q) {
                        float den = sq - sp;
                        den = (fabsf(den) < 1e-9f) ? 1e-9f : den;  // ref semantics
                        const float t = sq / den;
                        if (m < 8) {
                            vxs[cur^1][m][tid] = px + t*(cx - px);
                            vys[cur^1][m][tid] = py + t*(cy - py);
                        }
                        ++m;
                    }
                    if (in_p) {
                        if (m < 8) {
                            vxs[cur^1][m][tid] = cx;
                            vys[cur^1][m][tid] = cy;
                        }
                        ++m;
                    }
                    px = cx; py = cy; sq = sp;
                }
            }
        }
        n = m;
        cur ^= 1;
    }

    float area = 0.0f;
    if (n >= 3) {
        float s = 0.0f;
        const float x0 = vxs[cur][0][tid];
        const float y0 = vys[cur][0][tid];
        #pragma unroll
        for (int k = 0; k < 8; ++k) {
            if (k < n) {
                float nx, ny;
                if (k == n - 1) { nx = x0; ny = y0; }
                else {
                    int nk = k + 1; if (nk > 7) nk = 7;
                    nx = vxs[cur][nk][tid]; ny = vys[cur][nk][tid];
                }
                s += vxs[cur][k][tid]*ny - vys[cur][k][tid]*nx;
            }
        }
        area = 0.5f * fabsf(s);
    }

    const float zh = fminf(az + adz*0.5f, bz + bdz*0.5f);
    const float zl = fmaxf(az - adz*0.5f, bz - bdz*0.5f);
    const float h = fmaxf(zh - zl, 0.0f);
    const float inter = area * h;
    const float va = adx*ady*adz;
    const float vb = bdx*bdy*bdz;
    const float iou = inter / fmaxf(va + vb - inter, 1e-6f);

    const unsigned long long bal = __ballot(iou > IOU_THR_F);
    if ((tid & 63) == 0) {
        const int w = j >> 6;
        maskrow[(size_t)i*NW + w] = bal;
        rowflag[i*NW + w] = (bal != 0ull) ? 1 : 0;
    }
}

// ---------------------------------------------------------------------------
// K2: clustering, bit-parallel chunked, sparsity-aware. 1 block x 256 threads.
// Only words flagged nonzero are staged/read; zero words never touched.
// ---------------------------------------------------------------------------
__global__ __launch_bounds__(256) void cluster_kernel(
    const unsigned long long* __restrict__ maskrow,
    const unsigned char* __restrict__ rowflag,
    int* __restrict__ ci_out)
{
    extern __shared__ char smem[];
    unsigned long long* mat = (unsigned long long*)smem;                  // 128 KB (sparse-filled)
    unsigned short* wm = (unsigned short*)(smem + 131072);                // 1024 u16 = 2 KB
    int* ci_lds = (int*)(smem + 133120);                                  // 1024 int = 4 KB
    unsigned long long* seedmask = (unsigned long long*)(smem + 137216);  // 16 u64
    int* rankbase = (int*)(smem + 137344);                                // 16 int

    const int tid = threadIdx.x;

    // ---- phase A: compact staging (only flagged words) ----
    for (int i = tid; i < NB; i += 256) ci_lds[i] = 0;
    #pragma unroll
    for (int rr = 0; rr < 4; ++rr) {
        const int r = tid + rr * 256;
        const uint4 f = *(const uint4*)(rowflag + r * NW);   // 16 flag bytes
        unsigned int m16 = 0;
        #define NIBX(v, sh) \
            { if ((v) & 0x000000FFu) m16 |= 1u << (sh); \
              if ((v) & 0x0000FF00u) m16 |= 1u << ((sh)+1); \
              if ((v) & 0x00FF0000u) m16 |= 1u << ((sh)+2); \
              if ((v) & 0xFF000000u) m16 |= 1u << ((sh)+3); }
        NIBX(f.x, 0) NIBX(f.y, 4) NIBX(f.z, 8) NIBX(f.w, 12)
        #undef NIBX
        wm[r] = (unsigned short)m16;
        unsigned int t16 = m16;
        while (t16) {
            const int w = __ffs(t16) - 1;
            t16 &= t16 - 1;
            mat[widx(r, w)] = maskrow[r * NW + w];
        }
    }
    __syncthreads();

    // ---- phase B: wave 0 only, serial-chunk greedy (exact ref semantics) ----
    if (tid < 64) {
        unsigned long long zm[NW];
        #pragma unroll
        for (int w = 0; w < NW; ++w) zm[w] = ~0ull;
        int base = 0;

        #pragma unroll
        for (int c = 0; c < NW; ++c) {
            const unsigned long long selfbit = 1ull << tid;
            const unsigned long long D = mat[widx(c * 64 + tid, c)];  // diag always flagged
            unsigned long long U = D & ~selfbit;
            #pragma unroll
            for (int off = 1; off < 64; off <<= 1)
                U |= __shfl_xor(U, off);
            const unsigned long long A = __ballot(D == selfbit) & ~U;

            unsigned long long E = zm[c];
            unsigned long long S = E & A;       // safe seeds
            unsigned long long rem = E & ~A;    // serial part
            while (rem) {
                const int t = __ffsll(rem) - 1;
                rem &= rem - 1;
                if ((E >> t) & 1ull) {
                    S |= 1ull << t;
                    const unsigned long long Dt = __shfl(D, t);
                    E &= ~Dt;
                    rem &= E;
                }
            }

            if (tid == 0) { seedmask[c] = S; rankbase[c] = base; }
            base += (int)__popcll(S);

            // word-occupancy of SEED rows only -> skip all-zero clear words
            const unsigned int myWm = (unsigned int)wm[c * 64 + tid];
            const bool isSeed = ((S >> tid) & 1ull) != 0ull;
            unsigned int wmS = isSeed ? myWm : 0u;
            unsigned int Wall = wmS;
            #pragma unroll
            for (int off = 1; off < 64; off <<= 1)
                Wall |= __shfl_xor(Wall, off);

            #pragma unroll
            for (int w = c + 1; w < NW; ++w) {          // static w -> zm stays in regs
                if ((Wall >> w) & 1u) {                  // wave-uniform branch
                    unsigned long long v =
                        ((wmS >> w) & 1u) ? mat[widx(c * 64 + tid, w)] : 0ull;
                    #pragma unroll
                    for (int off = 1; off < 64; off <<= 1)
                        v |= __shfl_xor(v, off);
                    zm[w] &= ~v;
                }
            }
        }
    }
    __syncthreads();

    // ---- phase C: label = max rank over covering seed rows (flagged words only) ----
    for (int r = tid; r < NB; r += 256) {
        const unsigned long long S = seedmask[r >> 6];
        const int pos = r & 63;
        if ((S >> pos) & 1ull) {
            const int rank = rankbase[r >> 6]
                           + (int)__popcll(S & ((1ull << pos) - 1ull)) + 1;
            unsigned int f = (unsigned int)wm[r];
            while (f) {
                const int w = __ffs(f) - 1;
                f &= f - 1;
                unsigned long long bits = mat[widx(r, w)];
                while (bits) {
                    const int j = __ffsll(bits) - 1;
                    bits &= bits - 1;
                    atomicMax(&ci_lds[(w << 6) + j], rank);
                }
            }
        }
    }
    __syncthreads();
    for (int i = tid; i < NB; i += 256) ci_out[i] = ci_lds[i];
}

// ---------------------------------------------------------------------------
// K3: per-cluster fusion. 1024 blocks x 64 threads (1 wave).
// ---------------------------------------------------------------------------
__global__ __launch_bounds__(64) void fuse_kernel(
    const float* __restrict__ boxes,
    const float* __restrict__ scores,
    const int* __restrict__ ci,
    float* __restrict__ out)
{
    __shared__ float ms[NB];
    __shared__ int   mi[NB];

    const int b = blockIdx.x;
    const int lane = threadIdx.x;
    const int target = b + 1;

    unsigned int mymask = 0;
    #pragma unroll
    for (int k = 0; k < 16; ++k) {
        const int idx = lane * 16 + k;
        if (ci[idx] == target) mymask |= (1u << k);
    }
    const bool anyv = (__ballot(mymask != 0) != 0ULL);

    float* outb = out + (size_t)b * 7;
    float* outs = out + 7 * NB;
    float* outv = out + 8 * NB;

    if (!anyv) {
        if (lane == 0) {
            #pragma unroll
            for (int c = 0; c < 7; ++c) outb[c] = 0.0f;
            outs[b] = 0.0f;
            outv[b] = 0.0f;
        }
        return;
    }

    // pass 1: ssum + argmax (first index of max)
    float ssum = 0.0f, smax = -1.0f;
    int sidx = 1 << 30;
    #pragma unroll
    for (int k = 0; k < 16; ++k) {
        if (mymask & (1u << k)) {
            const int idx = lane * 16 + k;
            const float s = scores[idx];
            ssum += s;
            if (s > smax || (s == smax && idx < sidx)) { smax = s; sidx = idx; }
        }
    }
    #pragma unroll
    for (int off = 32; off >= 1; off >>= 1) {
        ssum += __shfl_xor(ssum, off);
        const float om = __shfl_xor(smax, off);
        const int   oi = __shfl_xor(sidx, off);
        if (om > smax || (om == smax && oi < sidx)) { smax = om; sidx = oi; }
    }
    const float ref = limit_period_f(boxes[sidx * 7 + 6]);

    // pass 2: sc_gt
    float sc_gt = 0.0f;
    #pragma unroll
    for (int k = 0; k < 16; ++k) {
        if (mymask & (1u << k)) {
            const int idx = lane * 16 + k;
            const float dir = limit_period_f(boxes[idx * 7 + 6]);
            float diff = fabsf(dir - ref);
            if (diff > PI_F) diff = 2.0f * PI_F - diff;
            if (diff > PI_F * 0.5f) sc_gt += scores[idx];
        }
    }
    #pragma unroll
    for (int off = 32; off >= 1; off >>= 1) sc_gt += __shfl_xor(sc_gt, off);
    const bool flip_gt = (sc_gt <= (ssum - sc_gt));

    // pass 3: weighted sums (6 center comps + sin + cos)
    float acc[6] = {0,0,0,0,0,0};
    float ssin = 0.0f, scos = 0.0f;
    #pragma unroll
    for (int k = 0; k < 16; ++k) {
        if (mymask & (1u << k)) {
            const int idx = lane * 16 + k;
            const float s = scores[idx];
            const float w = s / ssum;
            const float dir = limit_period_f(boxes[idx * 7 + 6]);
            float diff = fabsf(dir - ref);
            if (diff > PI_F) diff = 2.0f * PI_F - diff;
            const bool gt = (diff > PI_F * 0.5f);
            const bool add = flip_gt ? gt : (!gt);
            const float d2 = limit_period_f(dir + (add ? PI_F : 0.0f));
            float sd, cd;
            sincosf(d2, &sd, &cd);
            ssin += sd * w;
            scos += cd * w;
            #pragma unroll
            for (int c = 0; c < 6; ++c) acc[c] += boxes[idx * 7 + c] * w;
        }
    }
    #pragma unroll
    for (int off = 32; off >= 1; off >>= 1) {
        ssin += __shfl_xor(ssin, off);
        scos += __shfl_xor(scos, off);
        #pragma unroll
        for (int c = 0; c < 6; ++c) acc[c] += __shfl_xor(acc[c], off);
    }
    const float theta = atan2f(ssin, scos);

    // pass 4: score fusion via tie-broken ranks (matches sorted-power sum)
    const int cnt = __popc(mymask);
    int x = cnt;
    #pragma unroll
    for (int off = 1; off < 64; off <<= 1) {
        const int y = __shfl_up(x, off);
        if (lane >= off) x += y;
    }
    const int base = x - cnt;
    const int K = __shfl(x, 63);
    {
        int p = base;
        #pragma unroll
        for (int k = 0; k < 16; ++k) {
            if (mymask & (1u << k)) {
                const int idx = lane * 16 + k;
                ms[p] = scores[idx];
                mi[p] = idx;
                ++p;
            }
        }
    }
    __syncthreads();

    float sf = 0.0f;
    for (int e = lane; e < K; e += 64) {
        const float v = ms[e];
        const int ix = mi[e];
        int rank = 0;
        for (int t = 0; t < K; ++t) {
            const float u = ms[t];
            if (u > v || (u == v && mi[t] < ix)) ++rank;
        }
        sf += powf(v, (float)(rank + 1));
    }
    #pragma unroll
    for (int off = 32; off >= 1; off >>= 1) sf += __shfl_xor(sf, off);
    sf = fminf(sf, 1.0f);

    if (lane == 0) {
        #pragma unroll
        for (int c = 0; c < 6; ++c) outb[c] = acc[c];
        outb[6] = theta;
        outs[b] = sf;
        outv[b] = 1.0f;
    }
}

// ---------------------------------------------------------------------------
extern "C" void kernel_launch(void* const* d_in, const int* in_sizes, int n_in,
                              void* d_out, int out_size, void* d_ws, size_t ws_size,
                              hipStream_t stream) {
    const float* boxes  = (const float*)d_in[0];   // (1024,7) f32
    const float* scores = (const float*)d_in[1];   // (1024,)  f32
    float* out = (float*)d_out;

    unsigned long long* maskrow = (unsigned long long*)d_ws;                 // 128 KB
    int* ci = (int*)((char*)d_ws + 131072);                                  // 4 KB
    unsigned char* rowflag = (unsigned char*)d_ws + 135168;                  // 16 KB

    dim3 g1(4, NB, 1);
    iou_mask_kernel<<<g1, 256, 0, stream>>>(boxes, maskrow, rowflag);

    const size_t SMEM = 137408;  // 128K mat + 2K wm + 4K ci + seedmask/rankbase
    (void)hipFuncSetAttribute((const void*)cluster_kernel,
                              hipFuncAttributeMaxDynamicSharedMemorySize, (int)SMEM);
    cluster_kernel<<<1, 256, SMEM, stream>>>(maskrow, rowflag, ci);

    fuse_kernel<<<NB, 64, 0, stream>>>(boxes, scores, ci, out);
}

// Round 4
// 91.058 us; speedup vs baseline: 1.4716x; 1.4716x over previous
//
#include <hip/hip_runtime.h>

#define PI_F 3.141592653f
#define NB 1024
#define NW 16            // 16 x u64 words per 1024-bit row
#define IOU_THR_F 0.1f

__device__ __forceinline__ float limit_period_f(float v) {
    return v - floorf(v / (2.0f * PI_F) + 0.5f) * (2.0f * PI_F);
}

// swizzled word index: word w of row r lives at r*16 + (w ^ (r&15))
__device__ __forceinline__ int widx(int r, int w) {
    return (r << 4) | (w ^ (r & 15));
}

// ---------------------------------------------------------------------------
// K1T: per-pair rotated BEV IoU -> TRANSPOSED bit matrix + nonzero flags.
// Block = j (matT row, uniform B-box); lanes iterate i (4 per thread).
// matT[j] bit i == (iou3d_pair(boxes[i], boxes[j]) > 0.1)  -- identical FP
// expression per (i,j) as the row-major version, just a different thread map.
// Conservative circumradius prefilter skips the clip for ~99.5% of pairs.
// ---------------------------------------------------------------------------
__global__ __launch_bounds__(256) void iouT_kernel(
    const float* __restrict__ boxes,
    unsigned long long* __restrict__ maskT,
    unsigned char* __restrict__ flagT)
{
    __shared__ float vxs[2][8][256];
    __shared__ float vys[2][8][256];
    const int tid = threadIdx.x;
    const int j = blockIdx.x;

    // uniform B-box (second arg of iou3d_pair)
    const float xj  = boxes[j*7+0], yj  = boxes[j*7+1], zj  = boxes[j*7+2];
    const float dxj = boxes[j*7+3], dyj = boxes[j*7+4], dzj = boxes[j*7+5];
    const float bang = limit_period_f(boxes[j*7+6]);
    const float rb2 = 0.25f*(dxj*dxj + dyj*dyj);
    float cb, sb;
    sincosf(bang, &sb, &cb);

    // B corners (clip edges), uniform
    float pbx[4], pby[4];
    {
        const float hx = 0.5f*dxj, hy = 0.5f*dyj;
        const float lxs[4] = { hx, -hx, -hx, hx };
        const float lys[4] = { hy, hy, -hy, -hy };
        #pragma unroll
        for (int k = 0; k < 4; ++k) {
            pbx[k] = lxs[k]*cb - lys[k]*sb + xj;
            pby[k] = lxs[k]*sb + lys[k]*cb + yj;
        }
    }
    const float vb = dxj*dyj*dzj;

    #pragma unroll
    for (int q = 0; q < 4; ++q) {
        const int i = q*256 + tid;
        const float xi  = boxes[i*7+0], yi  = boxes[i*7+1];
        const float dxi = boxes[i*7+3], dyi = boxes[i*7+4];
        const float ddx = xi - xj, ddy = yi - yj;
        const float d2 = ddx*ddx + ddy*ddy;
        const float ra2 = 0.25f*(dxi*dxi + dyi*dyi);
        // d > rA+rB  =>  disjoint => iou = 0 => bit 0.  (ra+rb)^2 <= 2(ra2+rb2).
        const bool cand = d2 <= 2.0f*(ra2 + rb2);

        bool bit = false;
        if (__ballot(cand) != 0ull) {
            if (cand) {
                const float zi  = boxes[i*7+2], dzi = boxes[i*7+5];
                const float aang = limit_period_f(boxes[i*7+6]);
                float ca, sa;
                sincosf(aang, &sa, &ca);
                // A corners -> LDS buf 0 (per-lane column tid)
                {
                    const float hx = 0.5f*dxi, hy = 0.5f*dyi;
                    const float lxs[4] = { hx, -hx, -hx, hx };
                    const float lys[4] = { hy, hy, -hy, -hy };
                    #pragma unroll
                    for (int k = 0; k < 4; ++k) {
                        vxs[0][k][tid] = lxs[k]*ca - lys[k]*sa + xi;
                        vys[0][k][tid] = lxs[k]*sa + lys[k]*ca + yi;
                    }
                }

                int n = 4;
                int cur = 0;
                #pragma unroll
                for (int e = 0; e < 4; ++e) {
                    const float eax = pbx[e], eay = pby[e];
                    const float ebx2 = pbx[(e+1)&3], eby2 = pby[(e+1)&3];
                    const float dx = ebx2 - eax, dy = eby2 - eay;
                    int m = 0;
                    if (n > 0) {
                        int pidx = n - 1; if (pidx > 7) pidx = 7;
                        float px = vxs[cur][pidx][tid];
                        float py = vys[cur][pidx][tid];
                        float sq = dx*(py - eay) - dy*(px - eax);
                        #pragma unroll
                        for (int k = 0; k < 8; ++k) {
                            if (k < n) {
                                const float cx = vxs[cur][k][tid];
                                const float cy = vys[cur][k][tid];
                                const float sp = dx*(cy - eay) - dy*(cx - eax);
                                const bool in_p = (sp >= 0.0f);
                                const bool in_q = (sq >= 0.0f);
                                if (in_p != in_q) {
                                    float den = sq - sp;
                                    den = (fabsf(den) < 1e-9f) ? 1e-9f : den;
                                    const float t = sq / den;
                                    if (m < 8) {
                                        vxs[cur^1][m][tid] = px + t*(cx - px);
                                        vys[cur^1][m][tid] = py + t*(cy - py);
                                    }
                                    ++m;
                                }
                                if (in_p) {
                                    if (m < 8) {
                                        vxs[cur^1][m][tid] = cx;
                                        vys[cur^1][m][tid] = cy;
                                    }
                                    ++m;
                                }
                                px = cx; py = cy; sq = sp;
                            }
                        }
                    }
                    n = m;
                    cur ^= 1;
                }

                float area = 0.0f;
                if (n >= 3) {
                    float s = 0.0f;
                    const float x0 = vxs[cur][0][tid];
                    const float y0 = vys[cur][0][tid];
                    #pragma unroll
                    for (int k = 0; k < 8; ++k) {
                        if (k < n) {
                            float nx, ny;
                            if (k == n - 1) { nx = x0; ny = y0; }
                            else {
                                int nk = k + 1; if (nk > 7) nk = 7;
                                nx = vxs[cur][nk][tid]; ny = vys[cur][nk][tid];
                            }
                            s += vxs[cur][k][tid]*ny - vys[cur][k][tid]*nx;
                        }
                    }
                    area = 0.5f * fabsf(s);
                }

                const float zh = fminf(zi + dzi*0.5f, zj + dzj*0.5f);
                const float zl = fmaxf(zi - dzi*0.5f, zj - dzj*0.5f);
                const float h = fmaxf(zh - zl, 0.0f);
                const float inter = area * h;
                const float va = dxi*dyi*dzi;
                const float iou = inter / fmaxf(va + vb - inter, 1e-6f);
                bit = iou > IOU_THR_F;
            }
        }

        const unsigned long long bal = __ballot(bit);
        if ((tid & 63) == 0) {
            const int w = q*4 + (tid >> 6);
            maskT[(size_t)j*NW + w] = bal;
            flagT[j*NW + w] = (bal != 0ull) ? 1 : 0;
        }
    }
}

// ---------------------------------------------------------------------------
// K2: clustering via transposed matrix. 1 block x 256 threads.
// No butterflies, no serial shfl chain, no atomics:
//  - eligibility: pull  matT[j] & seeds_so_far  (sparse LDS reads)
//  - within-chunk greedy: ballot fixpoint (unique fixpoint = serial greedy)
//  - labels: rank of max-index covering seed
// ---------------------------------------------------------------------------
__global__ __launch_bounds__(256) void cluster_kernel(
    const unsigned long long* __restrict__ maskT,
    const unsigned char* __restrict__ flagT,
    int* __restrict__ ci_out)
{
    extern __shared__ char smem[];
    unsigned long long* mat = (unsigned long long*)smem;                 // 128 KB (sparse-filled)
    unsigned short* wm = (unsigned short*)(smem + 131072);               // 1024 u16
    unsigned long long* seed_lds = (unsigned long long*)(smem + 133120); // 16 u64
    int* rankb = (int*)(smem + 133248);                                  // 16 int

    const int tid = threadIdx.x;

    // ---- phase A: sparse staging of matT ----
    if (tid < NW) { seed_lds[tid] = 0ull; rankb[tid] = 0; }
    #pragma unroll
    for (int rr = 0; rr < 4; ++rr) {
        const int r = tid + rr * 256;
        const uint4 f = *(const uint4*)(flagT + r * NW);
        unsigned int m16 = 0;
        #define NIBX(v, sh) \
            { if ((v) & 0x000000FFu) m16 |= 1u << (sh); \
              if ((v) & 0x0000FF00u) m16 |= 1u << ((sh)+1); \
              if ((v) & 0x00FF0000u) m16 |= 1u << ((sh)+2); \
              if ((v) & 0xFF000000u) m16 |= 1u << ((sh)+3); }
        NIBX(f.x, 0) NIBX(f.y, 4) NIBX(f.z, 8) NIBX(f.w, 12)
        #undef NIBX
        wm[r] = (unsigned short)m16;
        unsigned int t16 = m16;
        while (t16) {
            const int w = __ffs(t16) - 1;
            t16 &= t16 - 1;
            mat[widx(r, w)] = maskT[r * NW + w];
        }
    }
    __syncthreads();

    // ---- phase B: wave 0, 16 sequential chunks ----
    if (tid < 64) {
        int base = 0;
        for (int c = 0; c < NW; ++c) {
            const int row = c * 64 + tid;
            unsigned int f = (unsigned int)wm[row];
            unsigned long long acc = 0ull, Dt = 0ull;
            while (f) {
                const int w = __ffs(f) - 1;
                f &= f - 1;
                const unsigned long long v = mat[widx(row, w)];
                acc |= v & seed_lds[w];          // seeds of future chunks are 0
                if (w == c) Dt = v;              // in-edges within my chunk (diag always flagged)
            }
            const bool elig = (acc == 0ull);
            const unsigned long long E = __ballot(elig);
            const unsigned long long inlow = Dt & ((1ull << tid) - 1ull);

            // ballot fixpoint: S(j) = E(j) && no seed t<j with edge t->j
            unsigned long long S = E;
            #pragma unroll 1
            for (int it = 0; it < 64; ++it) {
                const bool killed = (inlow & S) != 0ull;
                const unsigned long long S2 = E & __ballot(!killed);
                if (S2 == S) break;
                S = S2;
            }

            if (tid == 0) { seed_lds[c] = S; rankb[c] = base; }
            base += (int)__popcll(S);
        }
    }
    __syncthreads();

    // ---- phase C: label(j) = rank of max-index seed covering j ----
    #pragma unroll
    for (int rr = 0; rr < 4; ++rr) {
        const int r = tid + rr * 256;
        unsigned int f = (unsigned int)wm[r];
        int best = -1;
        while (f) {
            const int w = __ffs(f) - 1;
            f &= f - 1;
            const unsigned long long bits = mat[widx(r, w)] & seed_lds[w];
            if (bits) best = (w << 6) | (63 - __clzll(bits));  // w ascending -> monotone
        }
        int lbl = 0;
        if (best >= 0) {
            const int w = best >> 6, pos = best & 63;
            lbl = rankb[w] + (int)__popcll(seed_lds[w] & ((1ull << pos) - 1ull)) + 1;
        }
        ci_out[r] = lbl;
    }
}

// ---------------------------------------------------------------------------
// K3: per-cluster fusion. 1024 blocks x 64 threads (1 wave).
// ---------------------------------------------------------------------------
__global__ __launch_bounds__(64) void fuse_kernel(
    const float* __restrict__ boxes,
    const float* __restrict__ scores,
    const int* __restrict__ ci,
    float* __restrict__ out)
{
    __shared__ float ms[NB];
    __shared__ int   mi[NB];

    const int b = blockIdx.x;
    const int lane = threadIdx.x;
    const int target = b + 1;

    unsigned int mymask = 0;
    const int4* ci4 = (const int4*)ci;
    #pragma unroll
    for (int k4 = 0; k4 < 4; ++k4) {
        const int4 v = ci4[lane * 4 + k4];
        if (v.x == target) mymask |= 1u << (k4*4+0);
        if (v.y == target) mymask |= 1u << (k4*4+1);
        if (v.z == target) mymask |= 1u << (k4*4+2);
        if (v.w == target) mymask |= 1u << (k4*4+3);
    }
    const bool anyv = (__ballot(mymask != 0) != 0ULL);

    float* outb = out + (size_t)b * 7;
    float* outs = out + 7 * NB;
    float* outv = out + 8 * NB;

    if (!anyv) {
        if (lane == 0) {
            #pragma unroll
            for (int c = 0; c < 7; ++c) outb[c] = 0.0f;
            outs[b] = 0.0f;
            outv[b] = 0.0f;
        }
        return;
    }

    // pass 1: ssum + argmax (first index of max)
    float ssum = 0.0f, smax = -1.0f;
    int sidx = 1 << 30;
    #pragma unroll
    for (int k = 0; k < 16; ++k) {
        if (mymask & (1u << k)) {
            const int idx = lane * 16 + k;
            const float s = scores[idx];
            ssum += s;
            if (s > smax || (s == smax && idx < sidx)) { smax = s; sidx = idx; }
        }
    }
    #pragma unroll
    for (int off = 32; off >= 1; off >>= 1) {
        ssum += __shfl_xor(ssum, off);
        const float om = __shfl_xor(smax, off);
        const int   oi = __shfl_xor(sidx, off);
        if (om > smax || (om == smax && oi < sidx)) { smax = om; sidx = oi; }
    }
    const float ref = limit_period_f(boxes[sidx * 7 + 6]);

    // pass 2: sc_gt
    float sc_gt = 0.0f;
    #pragma unroll
    for (int k = 0; k < 16; ++k) {
        if (mymask & (1u << k)) {
            const int idx = lane * 16 + k;
            const float dir = limit_period_f(boxes[idx * 7 + 6]);
            float diff = fabsf(dir - ref);
            if (diff > PI_F) diff = 2.0f * PI_F - diff;
            if (diff > PI_F * 0.5f) sc_gt += scores[idx];
        }
    }
    #pragma unroll
    for (int off = 32; off >= 1; off >>= 1) sc_gt += __shfl_xor(sc_gt, off);
    const bool flip_gt = (sc_gt <= (ssum - sc_gt));

    // pass 3: weighted sums (6 center comps + sin + cos)
    float acc[6] = {0,0,0,0,0,0};
    float ssin = 0.0f, scos = 0.0f;
    #pragma unroll
    for (int k = 0; k < 16; ++k) {
        if (mymask & (1u << k)) {
            const int idx = lane * 16 + k;
            const float s = scores[idx];
            const float w = s / ssum;
            const float dir = limit_period_f(boxes[idx * 7 + 6]);
            float diff = fabsf(dir - ref);
            if (diff > PI_F) diff = 2.0f * PI_F - diff;
            const bool gt = (diff > PI_F * 0.5f);
            const bool add = flip_gt ? gt : (!gt);
            const float d2 = limit_period_f(dir + (add ? PI_F : 0.0f));
            float sd, cd;
            sincosf(d2, &sd, &cd);
            ssin += sd * w;
            scos += cd * w;
            #pragma unroll
            for (int c = 0; c < 6; ++c) acc[c] += boxes[idx * 7 + c] * w;
        }
    }
    #pragma unroll
    for (int off = 32; off >= 1; off >>= 1) {
        ssin += __shfl_xor(ssin, off);
        scos += __shfl_xor(scos, off);
        #pragma unroll
        for (int c = 0; c < 6; ++c) acc[c] += __shfl_xor(acc[c], off);
    }
    const float theta = atan2f(ssin, scos);

    // pass 4: score fusion via tie-broken ranks (matches sorted-power sum)
    const int cnt = __popc(mymask);
    int x = cnt;
    #pragma unroll
    for (int off = 1; off < 64; off <<= 1) {
        const int y = __shfl_up(x, off);
        if (lane >= off) x += y;
    }
    const int base = x - cnt;
    const int K = __shfl(x, 63);
    {
        int p = base;
        #pragma unroll
        for (int k = 0; k < 16; ++k) {
            if (mymask & (1u << k)) {
                const int idx = lane * 16 + k;
                ms[p] = scores[idx];
                mi[p] = idx;
                ++p;
            }
        }
    }
    __syncthreads();

    float sf = 0.0f;
    for (int e = lane; e < K; e += 64) {
        const float v = ms[e];
        const int ix = mi[e];
        int rank = 0;
        for (int t = 0; t < K; ++t) {
            const float u = ms[t];
            if (u > v || (u == v && mi[t] < ix)) ++rank;
        }
        sf += powf(v, (float)(rank + 1));
    }
    #pragma unroll
    for (int off = 32; off >= 1; off >>= 1) sf += __shfl_xor(sf, off);
    sf = fminf(sf, 1.0f);

    if (lane == 0) {
        #pragma unroll
        for (int c = 0; c < 6; ++c) outb[c] = acc[c];
        outb[6] = theta;
        outs[b] = sf;
        outv[b] = 1.0f;
    }
}

// ---------------------------------------------------------------------------
extern "C" void kernel_launch(void* const* d_in, const int* in_sizes, int n_in,
                              void* d_out, int out_size, void* d_ws, size_t ws_size,
                              hipStream_t stream) {
    const float* boxes  = (const float*)d_in[0];   // (1024,7) f32
    const float* scores = (const float*)d_in[1];   // (1024,)  f32
    float* out = (float*)d_out;

    unsigned long long* maskT = (unsigned long long*)d_ws;               // 128 KB
    int* ci = (int*)((char*)d_ws + 131072);                              // 4 KB
    unsigned char* flagT = (unsigned char*)d_ws + 135168;                // 16 KB

    iouT_kernel<<<NB, 256, 0, stream>>>(boxes, maskT, flagT);

    const size_t SMEM = 133312;  // 128K mat + 2K wm + seeds + rankbase
    (void)hipFuncSetAttribute((const void*)cluster_kernel,
                              hipFuncAttributeMaxDynamicSharedMemorySize, (int)SMEM);
    cluster_kernel<<<1, 256, SMEM, stream>>>(maskT, flagT, ci);

    fuse_kernel<<<NB, 64, 0, stream>>>(boxes, scores, ci, out);
}